// Round 1
// baseline (232.889 us; speedup 1.0000x reference)
//
#include <hip/hip_runtime.h>

#define N_NODES 50000
#define N_EDGES 800000
#define N_GRAPHS 256
#define D_FEAT 96
#define HIDDEN 32

// ---------------------------------------------------------------------------
// Kernel 1: y = x @ W1   (one thread per (node, hidden) element)
// Lanes within a 32-group share a node -> x reads broadcast, W1 reads coalesced.
__global__ void k_xw1(const float* __restrict__ x, const float* __restrict__ W1,
                      float* __restrict__ y) {
    int gid = blockIdx.x * blockDim.x + threadIdx.x;
    if (gid >= N_NODES * HIDDEN) return;
    int node = gid >> 5;
    int f = gid & 31;
    const float* xr = x + (size_t)node * D_FEAT;
    float acc = 0.f;
#pragma unroll
    for (int k = 0; k < D_FEAT; ++k)
        acc = fmaf(xr[k], W1[k * HIDDEN + f], acc);
    y[gid] = acc;
}

// ---------------------------------------------------------------------------
// Kernel 2: s[dst] += y[src] over edges. 32 lanes per edge (one per feature).
__global__ void k_scatter(const int* __restrict__ src, const int* __restrict__ dst,
                          const float* __restrict__ y, float* __restrict__ s) {
    int gid = blockIdx.x * blockDim.x + threadIdx.x;
    if (gid >= N_EDGES * HIDDEN) return;  // 25.6M < 2^31
    int e = gid >> 5;
    int f = gid & 31;
    int sn = src[e];
    int dn = dst[e];
    atomicAdd(&s[(size_t)dn * HIDDEN + f], y[(size_t)sn * HIDDEN + f]);
}

// ---------------------------------------------------------------------------
// Kernel 3: per-node MLP + mean-pool accumulation.
// Block = 256 threads = 8 nodes (32 lanes per node, lane = feature).
// batch is sorted -> LDS bucket window starting at batch[first node of block].
__global__ void __launch_bounds__(256)
k_mlp_pool(const float* __restrict__ y, const float* __restrict__ s,
           const int* __restrict__ batch,
           const float* __restrict__ b1, const float* __restrict__ W2,
           const float* __restrict__ b2,
           float* __restrict__ sums, float* __restrict__ counts) {
    const int GWIN = 16;
    __shared__ float w2s[HIDDEN * HIDDEN];   // 4 KB
    __shared__ float h1s[8][HIDDEN];         // 1 KB
    __shared__ float accs[GWIN * HIDDEN];    // 2 KB
    __shared__ float cnts[GWIN];

    int tid = threadIdx.x;
    for (int i = tid; i < HIDDEN * HIDDEN; i += 256) w2s[i] = W2[i];
    for (int i = tid; i < GWIN * HIDDEN; i += 256) accs[i] = 0.f;
    if (tid < GWIN) cnts[tid] = 0.f;

    int nodeBase = blockIdx.x * 8;           // grid = N_NODES/8 exactly (6250)
    int local = tid >> 5;                    // 0..7
    int f = tid & 31;
    int node = nodeBase + local;
    int gfirst = batch[nodeBase];

    __syncthreads();

    // h1 = ReLU(y + scatter + b1)
    float h1 = s[(size_t)node * HIDDEN + f] + y[(size_t)node * HIDDEN + f] + b1[f];
    h1 = fmaxf(h1, 0.f);
    h1s[local][f] = h1;
    __syncthreads();

    // h2 = ReLU(h1 @ W2 + b2)
    float h2 = b2[f];
#pragma unroll
    for (int k = 0; k < HIDDEN; ++k)
        h2 = fmaf(h1s[local][k], w2s[k * HIDDEN + f], h2);
    float h = fmaxf(h2, 0.f);

    int g = batch[node];
    int b = g - gfirst;                      // >= 0 (sorted)
    if (b < GWIN) {
        atomicAdd(&accs[b * HIDDEN + f], h);
        if (f == 0) atomicAdd(&cnts[b], 1.f);
    } else {
        atomicAdd(&sums[(size_t)g * HIDDEN + f], h);
        if (f == 0) atomicAdd(&counts[g], 1.f);
    }
    __syncthreads();

    // flush LDS buckets (skip zero contributions; adding 0 is a no-op anyway)
    for (int i = tid; i < GWIN * HIDDEN; i += 256) {
        float v = accs[i];
        if (v != 0.f) atomicAdd(&sums[(size_t)gfirst * HIDDEN + i], v);
    }
    if (tid < GWIN) {
        float c = cnts[tid];
        if (c != 0.f) atomicAdd(&counts[gfirst + tid], c);
    }
}

// ---------------------------------------------------------------------------
// Kernel 4: out[g] = (sums[g]/max(counts[g],1)) @ Wc + bc   (one thread/graph)
__global__ void k_out(const float* __restrict__ sums, const float* __restrict__ counts,
                      const float* __restrict__ Wc, const float* __restrict__ bc,
                      float* __restrict__ out) {
    int g = threadIdx.x;
    if (g >= N_GRAPHS) return;
    float inv = 1.f / fmaxf(counts[g], 1.f);
    float o0 = bc[0], o1 = bc[1];
#pragma unroll
    for (int k = 0; k < HIDDEN; ++k) {
        float p = sums[(size_t)g * HIDDEN + k] * inv;
        o0 = fmaf(p, Wc[k * 2 + 0], o0);
        o1 = fmaf(p, Wc[k * 2 + 1], o1);
    }
    out[g * 2 + 0] = o0;
    out[g * 2 + 1] = o1;
}

// ---------------------------------------------------------------------------
extern "C" void kernel_launch(void* const* d_in, const int* in_sizes, int n_in,
                              void* d_out, int out_size, void* d_ws, size_t ws_size,
                              hipStream_t stream) {
    const float* x     = (const float*)d_in[0];
    const int*   ei    = (const int*)d_in[1];   // [2, N_EDGES]: src row then dst row
    const int*   batch = (const int*)d_in[2];
    const float* W1    = (const float*)d_in[3];
    const float* b1    = (const float*)d_in[4];
    const float* W2    = (const float*)d_in[5];
    const float* b2    = (const float*)d_in[6];
    const float* Wc    = (const float*)d_in[7];
    const float* bc    = (const float*)d_in[8];
    float* out = (float*)d_out;

    // Workspace layout: [ y (1.6M f) | s (1.6M f) | sums (8192 f) | counts (256 f) ]
    float* y      = (float*)d_ws;
    float* s      = y + (size_t)N_NODES * HIDDEN;
    float* sums   = s + (size_t)N_NODES * HIDDEN;
    float* counts = sums + (size_t)N_GRAPHS * HIDDEN;

    size_t zero_bytes = ((size_t)N_NODES * HIDDEN + N_GRAPHS * HIDDEN + N_GRAPHS) * sizeof(float);
    hipMemsetAsync(s, 0, zero_bytes, stream);

    k_xw1<<<(N_NODES * HIDDEN + 255) / 256, 256, 0, stream>>>(x, W1, y);

    int total = N_EDGES * HIDDEN;  // 25,600,000
    k_scatter<<<(total + 255) / 256, 256, 0, stream>>>(ei, ei + N_EDGES, y, s);

    k_mlp_pool<<<N_NODES / 8, 256, 0, stream>>>(y, s, batch, b1, W2, b2, sums, counts);

    k_out<<<1, 256, 0, stream>>>(sums, counts, Wc, bc, out);
}

// Round 2
// 212.049 us; speedup vs baseline: 1.0983x; 1.0983x over previous
//
#include <hip/hip_runtime.h>

#define N_NODES 50000
#define N_EDGES 800000
#define N_GRAPHS 256
#define D_FEAT 96
#define HIDDEN 32
#define CAP 64   // max bucketed in-degree; overflow falls back to atomic s

// ---------------------------------------------------------------------------
// Kernel 1: y = x @ W1   (one thread per (node, hidden) element)
__global__ void k_xw1(const float* __restrict__ x, const float* __restrict__ W1,
                      float* __restrict__ y) {
    int gid = blockIdx.x * blockDim.x + threadIdx.x;
    int node = gid >> 5;
    int f = gid & 31;
    const float* xr = x + (size_t)node * D_FEAT;
    float acc = 0.f;
#pragma unroll
    for (int k = 0; k < D_FEAT; ++k)
        acc = fmaf(xr[k], W1[k * HIDDEN + f], acc);
    y[gid] = acc;
}

// ---------------------------------------------------------------------------
// Kernel 2: bucketize edges by dst. One thread per edge.
// 800K int atomics (vs 25.6M float atomics for direct scatter).
__global__ void k_bucket(const int* __restrict__ src, const int* __restrict__ dst,
                         const float* __restrict__ y,
                         int* __restrict__ count, unsigned short* __restrict__ slots,
                         int* __restrict__ ovf_flag, float* __restrict__ s) {
    int e = blockIdx.x * blockDim.x + threadIdx.x;
    if (e >= N_EDGES) return;
    int sn = src[e];
    int dn = dst[e];
    int slot = atomicAdd(&count[dn], 1);
    if (slot < CAP) {
        slots[(size_t)dn * CAP + slot] = (unsigned short)sn;
    } else {
        // overflow: direct accumulate into zeroed s (expected never at deg~Poisson(16))
        atomicAdd(ovf_flag, 1);
        for (int f = 0; f < HIDDEN; ++f)
            atomicAdd(&s[(size_t)dn * HIDDEN + f], y[(size_t)sn * HIDDEN + f]);
    }
}

// ---------------------------------------------------------------------------
// Kernel 3: fused gather + MLP + mean-pool accumulation.
// Block = 256 threads = 8 nodes (32 lanes/node, lane = feature).
__global__ void __launch_bounds__(256)
k_gather_mlp_pool(const float* __restrict__ y, const unsigned short* __restrict__ slots,
                  const int* __restrict__ count, const float* __restrict__ s,
                  const int* __restrict__ ovf_flag,
                  const int* __restrict__ batch,
                  const float* __restrict__ b1, const float* __restrict__ W2,
                  const float* __restrict__ b2,
                  float* __restrict__ sums, float* __restrict__ counts) {
    const int GWIN = 16;
    __shared__ float w2s[HIDDEN * HIDDEN];   // 4 KB
    __shared__ float h1s[8][HIDDEN];         // 1 KB
    __shared__ float accs[GWIN * HIDDEN];    // 2 KB
    __shared__ float cnts[GWIN];

    int tid = threadIdx.x;
    for (int i = tid; i < HIDDEN * HIDDEN; i += 256) w2s[i] = W2[i];
    for (int i = tid; i < GWIN * HIDDEN; i += 256) accs[i] = 0.f;
    if (tid < GWIN) cnts[tid] = 0.f;

    int nodeBase = blockIdx.x * 8;           // grid = 6250 exactly
    int local = tid >> 5;                    // 0..7
    int f = tid & 31;
    int node = nodeBase + local;
    int gfirst = batch[nodeBase];

    // GIN aggregation in-register: (x_i + sum_j x_j) @ W1 = y_i + sum_j y_j
    float acc = y[(size_t)node * HIDDEN + f];
    if (*ovf_flag) acc += s[(size_t)node * HIDDEN + f];
    int deg = count[node];
    if (deg > CAP) deg = CAP;
    const unsigned short* sl = slots + (size_t)node * CAP;
    int j = 0;
    for (; j + 4 <= deg; j += 4) {           // 4 independent y-row loads in flight
        ushort4 q = *(const ushort4*)(sl + j);
        float a0 = y[(size_t)q.x * HIDDEN + f];
        float a1 = y[(size_t)q.y * HIDDEN + f];
        float a2 = y[(size_t)q.z * HIDDEN + f];
        float a3 = y[(size_t)q.w * HIDDEN + f];
        acc += (a0 + a1) + (a2 + a3);
    }
    for (; j < deg; ++j)
        acc += y[(size_t)sl[j] * HIDDEN + f];

    float h1 = fmaxf(acc + b1[f], 0.f);
    h1s[local][f] = h1;
    __syncthreads();

    // h = ReLU(h1 @ W2 + b2)
    float h2 = b2[f];
#pragma unroll
    for (int k = 0; k < HIDDEN; ++k)
        h2 = fmaf(h1s[local][k], w2s[k * HIDDEN + f], h2);
    float h = fmaxf(h2, 0.f);

    // mean-pool accumulation; batch is sorted -> LDS window of 16 graphs
    int g = batch[node];
    int b = g - gfirst;
    if (b < GWIN) {
        atomicAdd(&accs[b * HIDDEN + f], h);
        if (f == 0) atomicAdd(&cnts[b], 1.f);
    } else {
        atomicAdd(&sums[(size_t)g * HIDDEN + f], h);
        if (f == 0) atomicAdd(&counts[g], 1.f);
    }
    __syncthreads();

    for (int i = tid; i < GWIN * HIDDEN; i += 256) {
        float v = accs[i];
        if (v != 0.f) atomicAdd(&sums[(size_t)gfirst * HIDDEN + i], v);
    }
    if (tid < GWIN) {
        float c = cnts[tid];
        if (c != 0.f) atomicAdd(&counts[gfirst + tid], c);
    }
}

// ---------------------------------------------------------------------------
// Kernel 4: out[g] = (sums[g]/max(counts[g],1)) @ Wc + bc
__global__ void k_out(const float* __restrict__ sums, const float* __restrict__ counts,
                      const float* __restrict__ Wc, const float* __restrict__ bc,
                      float* __restrict__ out) {
    int g = threadIdx.x;
    if (g >= N_GRAPHS) return;
    float inv = 1.f / fmaxf(counts[g], 1.f);
    float o0 = bc[0], o1 = bc[1];
#pragma unroll
    for (int k = 0; k < HIDDEN; ++k) {
        float p = sums[(size_t)g * HIDDEN + k] * inv;
        o0 = fmaf(p, Wc[k * 2 + 0], o0);
        o1 = fmaf(p, Wc[k * 2 + 1], o1);
    }
    out[g * 2 + 0] = o0;
    out[g * 2 + 1] = o1;
}

// ---------------------------------------------------------------------------
extern "C" void kernel_launch(void* const* d_in, const int* in_sizes, int n_in,
                              void* d_out, int out_size, void* d_ws, size_t ws_size,
                              hipStream_t stream) {
    const float* x     = (const float*)d_in[0];
    const int*   ei    = (const int*)d_in[1];   // [2, N_EDGES]: src row then dst row
    const int*   batch = (const int*)d_in[2];
    const float* W1    = (const float*)d_in[3];
    const float* b1    = (const float*)d_in[4];
    const float* W2    = (const float*)d_in[5];
    const float* b2    = (const float*)d_in[6];
    const float* Wc    = (const float*)d_in[7];
    const float* bc    = (const float*)d_in[8];
    float* out = (float*)d_out;

    // Workspace layout (byte offsets):
    //   0        count   50000 int   (200000 B)
    //   200000   sums    8192 f      (32768 B)
    //   232768   counts  256 f       (1024 B)
    //   233792   ovf_flag 1 int      (4 B) + 60 B pad
    //   233856   s       1.6M f      (6400000 B)   [overflow fallback accumulator]
    //   6633856  slots   50000*64 u16 (6400000 B)
    //   13033856 y       1.6M f      (6400000 B)
    // total 19433856 B
    char* ws = (char*)d_ws;
    int*   count    = (int*)ws;
    float* sums     = (float*)(ws + 200000);
    float* counts   = (float*)(ws + 232768);
    int*   ovf_flag = (int*)(ws + 233792);
    float* s        = (float*)(ws + 233856);
    unsigned short* slots = (unsigned short*)(ws + 6633856);
    float* y        = (float*)(ws + 13033856);

    // zero count+sums+counts+flag+s in one shot (slots validity bounded by count)
    hipMemsetAsync(d_ws, 0, 6633856, stream);

    k_xw1<<<N_NODES * HIDDEN / 256, 256, 0, stream>>>(x, W1, y);

    k_bucket<<<(N_EDGES + 255) / 256, 256, 0, stream>>>(ei, ei + N_EDGES, y,
                                                        count, slots, ovf_flag, s);

    k_gather_mlp_pool<<<N_NODES / 8, 256, 0, stream>>>(y, slots, count, s, ovf_flag,
                                                       batch, b1, W2, b2, sums, counts);

    k_out<<<1, 256, 0, stream>>>(sums, counts, Wc, bc, out);
}